// Round 9
// baseline (119.951 us; speedup 1.0000x reference)
//
#include <hip/hip_runtime.h>
#include <hip/hip_bf16.h>

typedef __attribute__((ext_vector_type(8))) short short8;
typedef __attribute__((ext_vector_type(4))) float f32x4;

#define DDIM 256
#define NROWS 131072
#define RG 256                // row-groups
#define GBLK (RG * 2)         // 512 blocks: bid = rg*2 + half (halves share L2/L3 X)
#define RPG (NROWS / RG)      // 512 rows per row-group
#define CHUNK 128             // rows per chunk (8 waves x 16 rows)
#define NSTEP 32              // 4 chunks x 8 kk-steps

static __device__ __forceinline__ unsigned short f2bf(float f){
  unsigned b = __builtin_bit_cast(unsigned, f);
  b += 0x7FFFu + ((b >> 16) & 1u);          // RNE round to bf16
  return (unsigned short)(b >> 16);
}

// Wave64 sum-reduction via DPP (VALU-only, ~45cy; chains pipeline when
// independent). row_shr 1/2/4/8 + row_bcast:15/31 -> total in lane 63.
static __device__ __forceinline__ float wave_sum_bcast(float x){
  int v = __builtin_bit_cast(int, x);
#define DPP_ADD(ctrl)                                                          \
  v = __builtin_bit_cast(int,                                                  \
        __builtin_bit_cast(float, v) +                                         \
        __builtin_bit_cast(float,                                              \
          __builtin_amdgcn_update_dpp(0, v, (ctrl), 0xF, 0xF, true)))
  DPP_ADD(0x111);  // row_shr:1
  DPP_ADD(0x112);  // row_shr:2
  DPP_ADD(0x114);  // row_shr:4
  DPP_ADD(0x118);  // row_shr:8
  DPP_ADD(0x142);  // row_bcast:15
  DPP_ADD(0x143);  // row_bcast:31
#undef DPP_ADD
  return __builtin_bit_cast(float, __builtin_amdgcn_readlane(v, 63));
}

// ---------------------------------------------------------------------------
// Kernel A: Q columns via 256 sequential Householder steps; 2 cols/wave.
// Depth-4 rotating prefetch of U rows hides load latency under ~80cy DPP
// bodies.  v.v reduced inline as a 3rd (pipelined) DPP chain + v_rcp
// (U rows unit-norm -> dv~1, rcp err ~1e-6 << bf16 noise).
// Writes Q^T (bf16) to Qt[n][k].
// ---------------------------------------------------------------------------
__global__ __launch_bounds__(256) void compute_q(const float* __restrict__ U,
                                                 unsigned short* __restrict__ Qt){
  const int lane = threadIdx.x & 63;
  const int wv   = threadIdx.x >> 6;          // 0..3
  const int pair = blockIdx.x * 4 + wv;       // 0..127
  const int j0 = pair * 2, j1 = j0 + 1;

  float u0[4], u1[4], r0[4], r1[4], r2[4], r3[4];
#pragma unroll
  for (int e = 0; e < 4; ++e){
    const int i = e * 64 + lane;
    u0[e] = (i == j0) ? 1.f : 0.f;
    u1[e] = (i == j1) ? 1.f : 0.f;
    r0[e] = U[0 * 256 + i];
    r1[e] = U[1 * 256 + i];
    r2[e] = U[2 * 256 + i];
    r3[e] = U[3 * 256 + i];
  }

#define QSTEP(R, KN)                                                           \
  do {                                                                         \
    const float p0_ = (u0[0]*R[0] + u0[1]*R[1]) + (u0[2]*R[2] + u0[3]*R[3]);   \
    const float p1_ = (u1[0]*R[0] + u1[1]*R[1]) + (u1[2]*R[2] + u1[3]*R[3]);   \
    const float pv_ = (R[0]*R[0] + R[1]*R[1]) + (R[2]*R[2] + R[3]*R[3]);       \
    const float d0_ = wave_sum_bcast(p0_);                                     \
    const float d1_ = wave_sum_bcast(p1_);                                     \
    const float dv_ = wave_sum_bcast(pv_);                                     \
    const float inv_ = 2.0f * __builtin_amdgcn_rcpf(dv_);                      \
    const float c0_ = d0_ * inv_, c1_ = d1_ * inv_;                            \
    _Pragma("unroll")                                                          \
    for (int e = 0; e < 4; ++e){                                               \
      u0[e] = fmaf(-c0_, R[e], u0[e]);                                         \
      u1[e] = fmaf(-c1_, R[e], u1[e]);                                         \
      R[e] = U[(size_t)(KN) * 256 + e * 64 + lane];                            \
    }                                                                          \
  } while (0)

  for (int k = 0; k < 256; k += 4){
    const int k4 = (k+4) & 255, k5 = (k+5) & 255, k6 = (k+6) & 255, k7 = (k+7) & 255;
    QSTEP(r0, k4);
    QSTEP(r1, k5);
    QSTEP(r2, k6);
    QSTEP(r3, k7);
  }
#undef QSTEP

#pragma unroll
  for (int e = 0; e < 4; ++e){
    const int i = e * 64 + lane;
    Qt[(size_t)j0 * 256 + i] = f2bf(u0[e]);
    Qt[(size_t)j1 * 256 + i] = f2bf(u1[e]);
  }
}

// ---------------------------------------------------------------------------
// Kernel B: Y = X * Q, persistent kk-pipelined.  512 blocks x 512 threads:
// bid = rg*2 + half; block owns 512 rows x 128 cols, processed as 4 chunks x
// 8 kk-steps, fully unrolled (32 steps).  Rotating depth-4 slot buffer of
// per-kk X loads keeps HBM continuously fed; the ONLY barrier (and its
// vmcnt(0) drain) is the one-time Qt stage.  Consecutive bids = two halves of
// the same rows -> duplicate X read is L2/L3-hot (verified r7: FETCH = 1x X).
// Full-row XOR swizzle ((nl&15)<<5) -> conflict-free (verified r5/r7: 0).
// 64 KiB LDS -> 2 blocks/CU; regs ~100/wave -> 4 waves/SIMD.
// mfma_f32_16x16x32_bf16 layouts (m89/m97):
//   A: lane holds A[l&15][kk*32+8*(l>>4)+j]   B: same, n=l&15
//   D: D[(l>>4)*4+r][l&15]
// ---------------------------------------------------------------------------
__global__ __launch_bounds__(512, 4) void gemm_xq(const float* __restrict__ X,
                                                  const unsigned short* __restrict__ Qt,
                                                  float* __restrict__ Y){
  __shared__ char qb[65536];                  // 128 rows (nl) x 512 B (k, bf16)

  const int tid  = threadIdx.x;
  const int lane = tid & 63;
  const int wv   = tid >> 6;                  // 0..7
  const int lg   = lane >> 4;                 // 0..3
  const int lm   = lane & 15;
  const int half = blockIdx.x & 1;
  const size_t rg = blockIdx.x >> 1;
  const size_t rowbase = rg * RPG;            // block's first row

  // --- Qt-half stage loads (issued first; ds_write waits only these 8) ---
  f32x4 sv[8];
#pragma unroll
  for (int it = 0; it < 8; ++it){
    const int c = tid + it * 512;             // 0..4095 chunks of 16B
    sv[it] = *reinterpret_cast<const f32x4*>(
        reinterpret_cast<const char*>(Qt) +
        ((size_t)(half * 128) << 9) + ((size_t)c << 4));
  }

  // lane's X base (chunk 0): row = rowbase + wv*16 + lm, col float lg*8
  const float* xl = X + (rowbase + wv * 16 + lm) * DDIM + lg * 8;

  f32x4 f[4][2];                              // rotating slots (static idx via unroll)
#define LDX(slot, s)                                                           \
  do {                                                                         \
    const float* p_ = xl + (size_t)((s) >> 3) * (CHUNK * DDIM) + ((s) & 7) * 32;\
    f[slot][0] = *reinterpret_cast<const f32x4*>(p_);                          \
    f[slot][1] = *reinterpret_cast<const f32x4*>(p_ + 4);                      \
  } while (0)

  // prologue: fill slots with steps 0..3
  LDX(0, 0); LDX(1, 1); LDX(2, 2); LDX(3, 3);

  // --- LDS writes (swizzled) + the single barrier ---
#pragma unroll
  for (int it = 0; it < 8; ++it){
    const int c   = tid + it * 512;
    const int n   = c >> 5;                   // local row nl (0..127)
    const int off = (c & 31) << 4;            // byte offset within 512B row
    *reinterpret_cast<f32x4*>(qb + (n << 9) + (off ^ ((n & 15) << 5))) = sv[it];
  }
  __syncthreads();

  f32x4 acc[8];
#pragma unroll
  for (int nt = 0; nt < 8; ++nt) acc[nt] = (f32x4){0.f, 0.f, 0.f, 0.f};

#pragma unroll
  for (int s = 0; s < NSTEP; ++s){
    // consume slot s&3: convert + 8 ds_read + 8 MFMA
    {
      const f32x4 lo = f[s & 3][0], hi = f[s & 3][1];
      short8 a;
      a[0] = (short)f2bf(lo[0]); a[1] = (short)f2bf(lo[1]);
      a[2] = (short)f2bf(lo[2]); a[3] = (short)f2bf(lo[3]);
      a[4] = (short)f2bf(hi[0]); a[5] = (short)f2bf(hi[1]);
      a[6] = (short)f2bf(hi[2]); a[7] = (short)f2bf(hi[3]);
      const int kb = (s & 7) * 64 + (lg << 4);
#pragma unroll
      for (int nt = 0; nt < 8; ++nt){
        const int nl = nt * 16 + lm;          // local col 0..127
        const short8 b = *reinterpret_cast<const short8*>(
            qb + (nl << 9) + (kb ^ ((nl & 15) << 5)));
        acc[nt] = __builtin_amdgcn_mfma_f32_16x16x32_bf16(a, b, acc[nt], 0, 0, 0);
      }
    }
    // reissue freed slot for step s+4 (keeps ~3 steps of HBM latency hidden)
    if (s + 4 < NSTEP) LDX(s & 3, s + 4);
    // chunk epilogue: store 16x128 result, reset acc
    if ((s & 7) == 7){
      const int c = s >> 3;
      const size_t orow = rowbase + (size_t)c * CHUNK + wv * 16 + lg * 4;
#pragma unroll
      for (int nt = 0; nt < 8; ++nt){
#pragma unroll
        for (int r = 0; r < 4; ++r){
          Y[(orow + r) * DDIM + half * 128 + nt * 16 + lm] = acc[nt][r];
        }
        acc[nt] = (f32x4){0.f, 0.f, 0.f, 0.f};
      }
    }
  }
#undef LDX
}

extern "C" void kernel_launch(void* const* d_in, const int* in_sizes, int n_in,
                              void* d_out, int out_size, void* d_ws, size_t ws_size,
                              hipStream_t stream) {
  const float* X = (const float*)d_in[0];     // [131072, 256]
  const float* U = (const float*)d_in[1];     // [256, 256]
  float* Y = (float*)d_out;                   // [131072, 256]
  unsigned short* Qt = (unsigned short*)d_ws; // 256*256 bf16 = 128 KB scratch

  compute_q<<<32, 256, 0, stream>>>(U, Qt);
  gemm_xq<<<GBLK, 512, 0, stream>>>(X, Qt, Y);
}